// Round 1
// baseline (198.980 us; speedup 1.0000x reference)
//
#include <hip/hip_runtime.h>

typedef _Float16 f16x8 __attribute__((ext_vector_type(8)));
typedef _Float16 f16x4 __attribute__((ext_vector_type(4)));
typedef float    f32x4 __attribute__((ext_vector_type(4)));

#define MFMA16(A, B, C) __builtin_amdgcn_mfma_f32_16x16x32_f16((A), (B), (C), 0, 0, 0)

constexpr int Bsz = 4096, Ssz = 200, INsz = 8, Hsz = 128, OUTsz = 8, Psz = 50;
constexpr int ROWS = 16;   // batch rows per block
constexpr int LDH  = 136;  // LDS row pitch in halves (128 + 8 pad -> 272B rows)

// split a fp32 8-vector into fp16 hi + fp16 residual fragments (register-resident)
#define SPLIT8(PTR, HI, LO) do { \
    const f32x4 va_ = *(const f32x4*)(PTR); \
    const f32x4 vb_ = *(const f32x4*)((PTR) + 4); \
    _Pragma("unroll") \
    for (int j_ = 0; j_ < 4; ++j_) { \
      _Float16 h0_ = (_Float16)va_[j_]; \
      (HI)[j_]     = h0_; \
      (LO)[j_]     = (_Float16)(va_[j_] - (float)h0_); \
      _Float16 h1_ = (_Float16)vb_[j_]; \
      (HI)[j_ + 4] = h1_; \
      (LO)[j_ + 4] = (_Float16)(vb_[j_] - (float)h1_); \
    } \
  } while (0)

// one matmul stage: z = act @ W^T + bias, swapped-operand MFMA (D = W * act^T)
// 3-product hi/lo split: uh*Wh + uh*Wl + ul*Wh  (fp32-equivalent precision)
#define STAGE(SH, SL, AH, AL, BI0, BI1, O0, O1) do { \
    f32x4 cA0_ = (BI0), cA1_ = (BI1); \
    f32x4 cB0_ = {0.f,0.f,0.f,0.f}, cB1_ = {0.f,0.f,0.f,0.f}; \
    _Pragma("unroll") \
    for (int ks_ = 0; ks_ < 4; ++ks_) { \
      const f16x8 uh_ = *(const f16x8*)(&(SH)[r][32*ks_ + 8*g]); \
      const f16x8 ul_ = *(const f16x8*)(&(SL)[r][32*ks_ + 8*g]); \
      cA0_ = MFMA16((AH)[0][ks_], uh_, cA0_); \
      cB0_ = MFMA16((AL)[0][ks_], uh_, cB0_); \
      cB0_ = MFMA16((AH)[0][ks_], ul_, cB0_); \
      cA1_ = MFMA16((AH)[1][ks_], uh_, cA1_); \
      cB1_ = MFMA16((AL)[1][ks_], uh_, cB1_); \
      cB1_ = MFMA16((AH)[1][ks_], ul_, cB1_); \
    } \
    (O0) = cA0_ + cB0_; (O1) = cA1_ + cB1_; \
  } while (0)

// write this lane's 8 channels (2 tiles x 4 consecutive chans) of one batch row
// to the hi/lo LDS activation arrays (ds_write_b64 each)
#define WRITE2(DH, DL, V0, V1) do { \
    f16x4 wh_, wl_; \
    _Pragma("unroll") \
    for (int q_ = 0; q_ < 4; ++q_) { \
      _Float16 hh_ = (_Float16)(V0)[q_]; \
      wh_[q_] = hh_; wl_[q_] = (_Float16)((V0)[q_] - (float)hh_); \
    } \
    *(f16x4*)(&(DH)[r][ch0 + 4*g])      = wh_; \
    *(f16x4*)(&(DL)[r][ch0 + 4*g])      = wl_; \
    _Pragma("unroll") \
    for (int q_ = 0; q_ < 4; ++q_) { \
      _Float16 hh_ = (_Float16)(V1)[q_]; \
      wh_[q_] = hh_; wl_[q_] = (_Float16)((V1)[q_] - (float)hh_); \
    } \
    *(f16x4*)(&(DH)[r][ch0 + 16 + 4*g]) = wh_; \
    *(f16x4*)(&(DL)[r][ch0 + 16 + 4*g]) = wl_; \
  } while (0)

__device__ inline f32x4 tanh4(f32x4 z) {
  f32x4 o;
  #pragma unroll
  for (int q = 0; q < 4; ++q) {
    float zz = fminf(fmaxf(z[q], -15.f), 15.f);
    float e  = __builtin_amdgcn_exp2f(2.8853900817779268f * zz); // e^(2x)
    o[q] = (e - 1.f) * __builtin_amdgcn_rcpf(e + 1.f);
  }
  return o;
}

__global__ __launch_bounds__(256, 1) void node_rk4_kernel(
    const float* __restrict__ x,    const float* __restrict__ Win,
    const float* __restrict__ binp, const float* __restrict__ W1,
    const float* __restrict__ b1,   const float* __restrict__ W2,
    const float* __restrict__ b2,   const float* __restrict__ Wout,
    const float* __restrict__ bout, float* __restrict__ out)
{
  __shared__ _Float16 u_hi[ROWS][LDH], u_lo[ROWS][LDH]; // current ODE input y/u
  __shared__ _Float16 t_hi[ROWS][LDH], t_lo[ROWS][LDH]; // tanh hidden

  const int tid = (int)threadIdx.x;
  const int w   = tid >> 6;   // wave 0..3, owns channels [32w, 32w+32)
  const int l   = tid & 63;
  const int g   = l >> 4;     // lane quarter
  const int r   = l & 15;     // batch row within tile (also frag row/col)
  const int rowbase = (int)blockIdx.x * ROWS;
  const int ch0 = w * 32;

  // ---------- preload weight fragments (registers) ----------
  // A-frag mapping: lane holds W[ch0+16t+(l&15)][32ks + 8*(l>>4) + j], j=0..7
  f16x8 a1h[2][4], a1l[2][4], a2h[2][4], a2l[2][4], aoh[4], aol[4];
  #pragma unroll
  for (int t = 0; t < 2; ++t) {
    #pragma unroll
    for (int ks = 0; ks < 4; ++ks) {
      const int hch = ch0 + 16*t + r;
      const int kb  = 32*ks + 8*g;
      SPLIT8(W1 + (size_t)hch*Hsz + kb, a1h[t][ks], a1l[t][ks]);
      SPLIT8(W2 + (size_t)hch*Hsz + kb, a2h[t][ks], a2l[t][ks]);
    }
  }
  #pragma unroll
  for (int ks = 0; ks < 4; ++ks) {          // Wout padded to 16 rows with zeros
    if (r < OUTsz) {
      SPLIT8(Wout + (size_t)r*Hsz + 32*ks + 8*g, aoh[ks], aol[ks]);
    } else {
      #pragma unroll
      for (int j = 0; j < 8; ++j) { aoh[ks][j] = (_Float16)0.f; aol[ks][j] = (_Float16)0.f; }
    }
  }

  // bias vectors: acc reg q <-> channel ch0+16t+4g+q ; out chan o = 4g+q
  const f32x4 b1v0 = *(const f32x4*)(b1 + ch0 + 4*g);
  const f32x4 b1v1 = *(const f32x4*)(b1 + ch0 + 16 + 4*g);
  const f32x4 b2v0 = *(const f32x4*)(b2 + ch0 + 4*g);
  const f32x4 b2v1 = *(const f32x4*)(b2 + ch0 + 16 + 4*g);
  f32x4 boutv;
  if (g < 2) boutv = *(const f32x4*)(bout + 4*g);
  else { boutv[0] = boutv[1] = boutv[2] = boutv[3] = 0.f; }

  // ---------- h0 = x[:, S-1, :] @ Win^T + bin (only last timestep matters) ----------
  const float* xr = x + ((size_t)(rowbase + r)*Ssz + (Ssz - 1))*INsz;
  const f32x4 xa = *(const f32x4*)xr;
  const f32x4 xb = *(const f32x4*)(xr + 4);
  f32x4 y0, y1;  // fp32 master state: lane owns 8 chans of batch row r
  #pragma unroll
  for (int t = 0; t < 2; ++t) {
    const f32x4 binv = *(const f32x4*)(binp + ch0 + 16*t + 4*g);
    f32x4 yv;
    #pragma unroll
    for (int q = 0; q < 4; ++q) {
      const float* wrp = Win + (size_t)(ch0 + 16*t + 4*g + q)*INsz;
      const f32x4 wa = *(const f32x4*)wrp;
      const f32x4 wb = *(const f32x4*)(wrp + 4);
      float acc = binv[q];
      #pragma unroll
      for (int i = 0; i < 4; ++i) acc += xa[i]*wa[i] + xb[i]*wb[i];
      yv[q] = acc;
    }
    if (t == 0) y0 = yv; else y1 = yv;
  }

  WRITE2(u_hi, u_lo, y0, y1);
  __syncthreads();

  f32x4 kacc0, kacc1;

  #pragma unroll 1
  for (int p = 0; p < Psz; ++p) {
    // ----- output projection of current y (wave 0), overlaps stage A of others -----
    if (w == 0) {
      f32x4 pA = boutv;
      f32x4 pB = {0.f,0.f,0.f,0.f};
      #pragma unroll
      for (int ks = 0; ks < 4; ++ks) {
        const f16x8 yh = *(const f16x8*)(&u_hi[r][32*ks + 8*g]);
        const f16x8 yl = *(const f16x8*)(&u_lo[r][32*ks + 8*g]);
        pA = MFMA16(aoh[ks], yh, pA);
        pB = MFMA16(aol[ks], yh, pB);
        pB = MFMA16(aoh[ks], yl, pB);
      }
      pA += pB;
      if (g < 2) {  // lane holds out row rowbase+r, chans 4g..4g+3
        float* dst = out + ((size_t)(rowbase + r)*Psz + p)*OUTsz + 4*g;
        *(f32x4*)dst = pA;
      }
    }
    if (p == Psz - 1) break;

    // ----- one RK4 step -----
    #pragma unroll
    for (int e = 0; e < 4; ++e) {
      f32x4 zA0, zA1;
      STAGE(u_hi, u_lo, a1h, a1l, b1v0, b1v1, zA0, zA1);  // u @ W1^T + b1
      zA0 = tanh4(zA0); zA1 = tanh4(zA1);
      WRITE2(t_hi, t_lo, zA0, zA1);
      __syncthreads();

      f32x4 k0, k1;
      STAGE(t_hi, t_lo, a2h, a2l, b2v0, b2v1, k0, k1);    // tanh @ W2^T + b2
      if      (e == 0) { kacc0  = k0;      kacc1  = k1;      }
      else if (e == 3) { kacc0 += k0;      kacc1 += k1;      }
      else             { kacc0 += 2.f*k0;  kacc1 += 2.f*k1;  }

      f32x4 u0, u1;
      if (e == 3) {
        y0 += (1.f/6.f) * kacc0; y1 += (1.f/6.f) * kacc1;
        u0 = y0; u1 = y1;
      } else {
        const float cw = (e == 2) ? 1.f : 0.5f;
        u0 = y0 + cw*k0; u1 = y1 + cw*k1;
      }
      WRITE2(u_hi, u_lo, u0, u1);
      __syncthreads();
    }
  }
}

extern "C" void kernel_launch(void* const* d_in, const int* in_sizes, int n_in,
                              void* d_out, int out_size, void* d_ws, size_t ws_size,
                              hipStream_t stream) {
  (void)in_sizes; (void)n_in; (void)d_ws; (void)ws_size; (void)out_size;
  const float* x    = (const float*)d_in[0];
  const float* Win  = (const float*)d_in[1];
  const float* binp = (const float*)d_in[2];
  const float* W1   = (const float*)d_in[3];
  const float* b1   = (const float*)d_in[4];
  const float* W2   = (const float*)d_in[5];
  const float* b2   = (const float*)d_in[6];
  const float* Wout = (const float*)d_in[7];
  const float* bout = (const float*)d_in[8];
  node_rk4_kernel<<<Bsz / ROWS, 256, 0, stream>>>(x, Win, binp, W1, b1, W2, b2,
                                                  Wout, bout, (float*)d_out);
}

// Round 2
// 138.075 us; speedup vs baseline: 1.4411x; 1.4411x over previous
//
#include <hip/hip_runtime.h>

typedef _Float16 f16x8 __attribute__((ext_vector_type(8)));
typedef _Float16 f16x4 __attribute__((ext_vector_type(4)));
typedef float    f32x4 __attribute__((ext_vector_type(4)));

#define MFMA16(A, B, C) __builtin_amdgcn_mfma_f32_16x16x32_f16((A), (B), (C), 0, 0, 0)

constexpr int Bsz = 4096, Ssz = 200, INsz = 8, Hsz = 128, OUTsz = 8, Psz = 50;
constexpr int ROWS = 16;   // batch rows per block
// d_ws layout (floats): G[128*128] @0 ; Go[8*128] @16384 ; d[128] @17408 ; co[8] @17536
constexpr int WS_G = 0, WS_GO = 16384, WS_D = 17408, WS_CO = 17536;

// ---------------- prologue: fold weight products ----------------
// G = W1@W2 (128x128), Go = Wout@W2 (8x128), d = W1@b2 (128), co = Wout@b2 (8)
__global__ void precomp_kernel(const float* __restrict__ W1, const float* __restrict__ W2,
                               const float* __restrict__ b2, const float* __restrict__ Wout,
                               float* __restrict__ ws) {
  int tid = (int)blockIdx.x * 256 + (int)threadIdx.x;
  if (tid < 16384) {                       // G[j][k]
    int j = tid >> 7, k = tid & 127;
    float acc = 0.f;
    #pragma unroll 8
    for (int m = 0; m < 128; ++m) acc = fmaf(W1[j*128 + m], W2[m*128 + k], acc);
    ws[WS_G + tid] = acc;
  } else if (tid < 16384 + 1024) {         // Go[o][k]
    int t = tid - 16384; int o = t >> 7, k = t & 127;
    float acc = 0.f;
    #pragma unroll 8
    for (int m = 0; m < 128; ++m) acc = fmaf(Wout[o*128 + m], W2[m*128 + k], acc);
    ws[WS_GO + t] = acc;
  } else if (tid < 16384 + 1024 + 128) {   // d[j] = sum_m b2[m]*W1[j][m]
    int j = tid - 17408;
    float acc = 0.f;
    for (int m = 0; m < 128; ++m) acc = fmaf(b2[m], W1[j*128 + m], acc);
    ws[WS_D + j] = acc;
  } else if (tid < 16384 + 1024 + 128 + 8) { // co[o] = sum_m b2[m]*Wout[o][m]
    int o = tid - 17536;
    float acc = 0.f;
    for (int m = 0; m < 128; ++m) acc = fmaf(b2[m], Wout[o*128 + m], acc);
    ws[WS_CO + o] = acc;
  }
}

// split fp32 x8 into fp16 hi + fp16 residual (register-resident weight frags)
#define SPLIT8(PTR, HI, LO) do { \
    const f32x4 va_ = *(const f32x4*)(PTR); \
    const f32x4 vb_ = *(const f32x4*)((PTR) + 4); \
    _Pragma("unroll") \
    for (int j_ = 0; j_ < 4; ++j_) { \
      _Float16 h0_ = (_Float16)va_[j_]; \
      (HI)[j_]     = h0_; \
      (LO)[j_]     = (_Float16)(va_[j_] - (float)h0_); \
      _Float16 h1_ = (_Float16)vb_[j_]; \
      (HI)[j_ + 4] = h1_; \
      (LO)[j_ + 4] = (_Float16)(vb_[j_] - (float)h1_); \
    } \
  } while (0)

// 2-tile matmul stage: O = frag(B) @ A^T + bias ; packed conflict-free LDS reads.
// 3-product hi/lo split, 6 independent MFMA chains of depth 4.
#define STG2(BH, BL, AH, AL, BI0, BI1, O0, O1) do { \
    f32x4 c0_ = (BI0), c1_ = (BI1); \
    f32x4 e0_ = {0.f,0.f,0.f,0.f}, e1_ = {0.f,0.f,0.f,0.f}; \
    f32x4 f0_ = {0.f,0.f,0.f,0.f}, f1_ = {0.f,0.f,0.f,0.f}; \
    _Pragma("unroll") \
    for (int ks_ = 0; ks_ < 4; ++ks_) { \
      const f16x8 uh_ = *(const f16x8*)(&(BH)[(ks_*64 + l)*8]); \
      const f16x8 ul_ = *(const f16x8*)(&(BL)[(ks_*64 + l)*8]); \
      c0_ = MFMA16((AH)[0][ks_], uh_, c0_); \
      e0_ = MFMA16((AL)[0][ks_], uh_, e0_); \
      f0_ = MFMA16((AH)[0][ks_], ul_, f0_); \
      c1_ = MFMA16((AH)[1][ks_], uh_, c1_); \
      e1_ = MFMA16((AL)[1][ks_], uh_, e1_); \
      f1_ = MFMA16((AH)[1][ks_], ul_, f1_); \
    } \
    (O0) = c0_ + e0_ + f0_; (O1) = c1_ + e1_ + f1_; \
  } while (0)

// 1-tile variant (output projection / o-update)
#define STG1(BH, BL, AH, AL, BI, O) do { \
    f32x4 c_ = (BI); \
    f32x4 e_ = {0.f,0.f,0.f,0.f}, f_ = {0.f,0.f,0.f,0.f}; \
    _Pragma("unroll") \
    for (int ks_ = 0; ks_ < 4; ++ks_) { \
      const f16x8 uh_ = *(const f16x8*)(&(BH)[(ks_*64 + l)*8]); \
      const f16x8 ul_ = *(const f16x8*)(&(BL)[(ks_*64 + l)*8]); \
      c_ = MFMA16((AH)[ks_], uh_, c_); \
      e_ = MFMA16((AL)[ks_], uh_, e_); \
      f_ = MFMA16((AH)[ks_], ul_, f_); \
    } \
    (O) = c_ + e_ + f_; \
  } while (0)

// write this lane's 8 channels (2 tiles) of one batch row into the packed
// hi/lo frag arrays at precomputed slot wb0 (tile1 at wb0+256)
#define W2PK(DH, DL, V0, V1) do { \
    f16x4 wh_, wl_; \
    _Pragma("unroll") \
    for (int q_ = 0; q_ < 4; ++q_) { \
      _Float16 hh_ = (_Float16)(V0)[q_]; \
      wh_[q_] = hh_; wl_[q_] = (_Float16)((V0)[q_] - (float)hh_); \
    } \
    *(f16x4*)(&(DH)[wb0])       = wh_; \
    *(f16x4*)(&(DL)[wb0])       = wl_; \
    _Pragma("unroll") \
    for (int q_ = 0; q_ < 4; ++q_) { \
      _Float16 hh_ = (_Float16)(V1)[q_]; \
      wh_[q_] = hh_; wl_[q_] = (_Float16)((V1)[q_] - (float)hh_); \
    } \
    *(f16x4*)(&(DH)[wb0 + 256]) = wh_; \
    *(f16x4*)(&(DL)[wb0 + 256]) = wl_; \
  } while (0)

__device__ inline f32x4 tanh4(f32x4 z) {
  f32x4 o;
  #pragma unroll
  for (int q = 0; q < 4; ++q) {
    float zz = fminf(fmaxf(z[q], -15.f), 15.f);
    float e  = __builtin_amdgcn_exp2f(2.8853900817779268f * zz); // e^(2x)
    o[q] = (e - 1.f) * __builtin_amdgcn_rcpf(e + 1.f);
  }
  return o;
}

__global__ __launch_bounds__(256, 1) void node_rk4_kernel(
    const float* __restrict__ x,    const float* __restrict__ Win,
    const float* __restrict__ binp, const float* __restrict__ W1,
    const float* __restrict__ b1,   const float* __restrict__ Wout,
    const float* __restrict__ bout, const float* __restrict__ ws,
    float* __restrict__ out)
{
  // packed frag buffers: slot (ks,lane) holds 8 halves = chans [32ks+8*(l>>4)..+8) of row l&15
  __shared__ _Float16 bufA_hi[2048], bufA_lo[2048], bufB_hi[2048], bufB_lo[2048];

  const int tid = (int)threadIdx.x;
  const int w   = tid >> 6;   // wave 0..3, owns channels [32w, 32w+32)
  const int l   = tid & 63;
  const int g   = l >> 4;
  const int r   = l & 15;     // batch row within tile
  const int rowbase = (int)blockIdx.x * ROWS;
  const int ch0 = w * 32;
  // packed write slot: chans 32w+4g+q of row r  (tile1 = +16 chans = +256 halves)
  const int wb0 = (w*64 + 16*(g >> 1) + r)*8 + 4*(g & 1);

  // ---------- persistent weight fragments ----------
  f16x8 Gh[2][4], Gl[2][4];        // G rows for this wave's 32 chans
  #pragma unroll
  for (int t = 0; t < 2; ++t)
    #pragma unroll
    for (int ks = 0; ks < 4; ++ks)
      SPLIT8(ws + WS_G + (size_t)(ch0 + 16*t + r)*Hsz + 32*ks + 8*g, Gh[t][ks], Gl[t][ks]);

  f16x8 goh[4], gol[4];            // Go rows (8 real, padded to 16) — used by wave 0
  #pragma unroll
  for (int ks = 0; ks < 4; ++ks) {
    if (r < OUTsz) SPLIT8(ws + WS_GO + (size_t)r*Hsz + 32*ks + 8*g, goh[ks], gol[ks]);
    else {
      #pragma unroll
      for (int j = 0; j < 8; ++j) { goh[ks][j] = (_Float16)0.f; gol[ks][j] = (_Float16)0.f; }
    }
  }

  // bias vectors (acc reg q <-> chan ch0+16t+4g+q)
  const f32x4 dv0  = *(const f32x4*)(ws + WS_D + ch0 + 4*g);
  const f32x4 dv1  = *(const f32x4*)(ws + WS_D + ch0 + 16 + 4*g);
  const f32x4 dv60 = 6.f * dv0, dv61 = 6.f * dv1;
  f32x4 cov6, boutv;
  if (g < 2) { cov6 = 6.f * *(const f32x4*)(ws + WS_CO + 4*g);
               boutv = *(const f32x4*)(bout + 4*g); }
  else { cov6 = f32x4{0.f,0.f,0.f,0.f}; boutv = f32x4{0.f,0.f,0.f,0.f}; }

  // ---------- y0 = x[:, S-1, :] @ Win^T + bin ----------
  const float* xr = x + ((size_t)(rowbase + r)*Ssz + (Ssz - 1))*INsz;
  const f32x4 xa = *(const f32x4*)xr;
  const f32x4 xb = *(const f32x4*)(xr + 4);
  f32x4 y0v, y1v;
  #pragma unroll
  for (int t = 0; t < 2; ++t) {
    const f32x4 binv = *(const f32x4*)(binp + ch0 + 16*t + 4*g);
    f32x4 yv;
    #pragma unroll
    for (int q = 0; q < 4; ++q) {
      const float* wrp = Win + (size_t)(ch0 + 16*t + 4*g + q)*INsz;
      const f32x4 wa = *(const f32x4*)wrp;
      const f32x4 wb = *(const f32x4*)(wrp + 4);
      float acc = binv[q];
      #pragma unroll
      for (int i = 0; i < 4; ++i) acc += xa[i]*wa[i] + xb[i]*wb[i];
      yv[q] = acc;
    }
    if (t == 0) y0v = yv; else y1v = yv;
  }

  W2PK(bufA_hi, bufA_lo, y0v, y1v);   // stage y0 frags
  __syncthreads();

  // ---------- init: z = y0@W1^T + b1 (all waves), o = y0@Wout^T (wave 0) ----------
  f32x4 z0, z1, o;
  {
    f16x8 a1h[2][4], a1l[2][4];       // transient W1 frags
    #pragma unroll
    for (int t = 0; t < 2; ++t)
      #pragma unroll
      for (int ks = 0; ks < 4; ++ks)
        SPLIT8(W1 + (size_t)(ch0 + 16*t + r)*Hsz + 32*ks + 8*g, a1h[t][ks], a1l[t][ks]);
    const f32x4 b1v0 = *(const f32x4*)(b1 + ch0 + 4*g);
    const f32x4 b1v1 = *(const f32x4*)(b1 + ch0 + 16 + 4*g);
    STG2(bufA_hi, bufA_lo, a1h, a1l, b1v0, b1v1, z0, z1);

    if (w == 0) {
      f16x8 woh[4], wol[4];           // transient Wout frags (padded)
      #pragma unroll
      for (int ks = 0; ks < 4; ++ks) {
        if (r < OUTsz) SPLIT8(Wout + (size_t)r*Hsz + 32*ks + 8*g, woh[ks], wol[ks]);
        else {
          #pragma unroll
          for (int j = 0; j < 8; ++j) { woh[ks][j] = (_Float16)0.f; wol[ks][j] = (_Float16)0.f; }
        }
      }
      const f32x4 zero = {0.f,0.f,0.f,0.f};
      STG1(bufA_hi, bufA_lo, woh, wol, zero, o);
    } else {
      o = f32x4{0.f,0.f,0.f,0.f};
    }
  }
  __syncthreads();   // bufA readers done before loop's s1 overwrites it

  // ---------- RK4 in z-space: 4 matmuls + 4 barriers per step ----------
  f32x4 Ta0, Ta1, m0, m1;
  #pragma unroll 1
  for (int p = 0; p < Psz; ++p) {
    if (w == 0 && g < 2) {   // out_p = o + bout
      float* dst = out + ((size_t)(rowbase + r)*Psz + p)*OUTsz + 4*g;
      *(f32x4*)dst = o + boutv;
    }
    if (p == Psz - 1) break;

    // s1: t1 = tanh(z) ; Ta = t1 ; -> bufA
    f32x4 t0 = tanh4(z0), t1 = tanh4(z1);
    Ta0 = t0; Ta1 = t1;
    W2PK(bufA_hi, bufA_lo, t0, t1);
    __syncthreads();

    // s2: m = t1@G^T + d ; z2 = z + 0.5m ; t2 -> bufB
    STG2(bufA_hi, bufA_lo, Gh, Gl, dv0, dv1, m0, m1);
    t0 = tanh4(z0 + 0.5f*m0); t1 = tanh4(z1 + 0.5f*m1);
    Ta0 += 2.f*t0; Ta1 += 2.f*t1;
    W2PK(bufB_hi, bufB_lo, t0, t1);
    __syncthreads();

    // s3: m = t2@G^T + d ; z3 = z + 0.5m ; t3 -> bufA
    STG2(bufB_hi, bufB_lo, Gh, Gl, dv0, dv1, m0, m1);
    t0 = tanh4(z0 + 0.5f*m0); t1 = tanh4(z1 + 0.5f*m1);
    Ta0 += 2.f*t0; Ta1 += 2.f*t1;
    W2PK(bufA_hi, bufA_lo, t0, t1);
    __syncthreads();

    // s4: m = t3@G^T + d ; z4 = z + m ; t4 ; T -> bufB
    STG2(bufA_hi, bufA_lo, Gh, Gl, dv0, dv1, m0, m1);
    t0 = tanh4(z0 + m0); t1 = tanh4(z1 + m1);
    Ta0 += t0; Ta1 += t1;
    W2PK(bufB_hi, bufB_lo, Ta0, Ta1);
    __syncthreads();

    // s5: z += (T@G^T + 6d)/6 ; wave0: o += (T@Go^T + 6co)/6
    STG2(bufB_hi, bufB_lo, Gh, Gl, dv60, dv61, m0, m1);
    z0 += (1.f/6.f)*m0; z1 += (1.f/6.f)*m1;
    if (w == 0) {
      f32x4 mo;
      STG1(bufB_hi, bufB_lo, goh, gol, cov6, mo);
      o += (1.f/6.f)*mo;
    }
    // no barrier: s1 writes bufA (last read pre-s4-barrier); s2's bufB write
    // is after s1's barrier, by which all s5 reads of bufB have drained.
  }
}

extern "C" void kernel_launch(void* const* d_in, const int* in_sizes, int n_in,
                              void* d_out, int out_size, void* d_ws, size_t ws_size,
                              hipStream_t stream) {
  (void)in_sizes; (void)n_in; (void)ws_size; (void)out_size;
  const float* x    = (const float*)d_in[0];
  const float* Win  = (const float*)d_in[1];
  const float* binp = (const float*)d_in[2];
  const float* W1   = (const float*)d_in[3];
  const float* b1   = (const float*)d_in[4];
  const float* W2   = (const float*)d_in[5];
  const float* b2   = (const float*)d_in[6];
  const float* Wout = (const float*)d_in[7];
  const float* bout = (const float*)d_in[8];
  float* ws = (float*)d_ws;

  precomp_kernel<<<69, 256, 0, stream>>>(W1, W2, b2, Wout, ws);
  node_rk4_kernel<<<Bsz / ROWS, 256, 0, stream>>>(x, Win, binp, W1, b1, Wout,
                                                  bout, ws, (float*)d_out);
}

// Round 3
// 105.721 us; speedup vs baseline: 1.8821x; 1.3060x over previous
//
#include <hip/hip_runtime.h>

typedef _Float16 f16x8 __attribute__((ext_vector_type(8)));
typedef _Float16 f16x4 __attribute__((ext_vector_type(4)));
typedef float    f32x4 __attribute__((ext_vector_type(4)));

#define MFMA16(A, B, C) __builtin_amdgcn_mfma_f32_16x16x32_f16((A), (B), (C), 0, 0, 0)

constexpr int Bsz = 4096, Ssz = 200, INsz = 8, Hsz = 128, OUTsz = 8, Psz = 50;
constexpr int ROWS = 16;   // batch rows per block
// d_ws layout (floats): G[128*128] @0 ; Go[8*128] @16384 ; d[128] @17408 ; co[8] @17536
constexpr int WS_G = 0, WS_GO = 16384, WS_D = 17408, WS_CO = 17536;

// ---------------- prologue: fold weight products ----------------
// G = W1@W2 (128x128), Go = Wout@W2 (8x128), d = W1@b2 (128), co = Wout@b2 (8)
__global__ void precomp_kernel(const float* __restrict__ W1, const float* __restrict__ W2,
                               const float* __restrict__ b2, const float* __restrict__ Wout,
                               float* __restrict__ ws) {
  int tid = (int)blockIdx.x * 256 + (int)threadIdx.x;
  if (tid < 16384) {                       // G[j][k]
    int j = tid >> 7, k = tid & 127;
    float acc = 0.f;
    #pragma unroll 8
    for (int m = 0; m < 128; ++m) acc = fmaf(W1[j*128 + m], W2[m*128 + k], acc);
    ws[WS_G + tid] = acc;
  } else if (tid < 16384 + 1024) {         // Go[o][k]
    int t = tid - 16384; int o = t >> 7, k = t & 127;
    float acc = 0.f;
    #pragma unroll 8
    for (int m = 0; m < 128; ++m) acc = fmaf(Wout[o*128 + m], W2[m*128 + k], acc);
    ws[WS_GO + t] = acc;
  } else if (tid < 16384 + 1024 + 128) {   // d[j] = sum_m b2[m]*W1[j][m]
    int j = tid - 17408;
    float acc = 0.f;
    for (int m = 0; m < 128; ++m) acc = fmaf(b2[m], W1[j*128 + m], acc);
    ws[WS_D + j] = acc;
  } else if (tid < 16384 + 1024 + 128 + 8) { // co[o] = sum_m b2[m]*Wout[o][m]
    int o = tid - 17536;
    float acc = 0.f;
    for (int m = 0; m < 128; ++m) acc = fmaf(b2[m], Wout[o*128 + m], acc);
    ws[WS_CO + o] = acc;
  }
}

// split fp32 x8 into fp16 hi + fp16 residual (register-resident weight frags)
#define SPLIT8(PTR, HI, LO) do { \
    const f32x4 va_ = *(const f32x4*)(PTR); \
    const f32x4 vb_ = *(const f32x4*)((PTR) + 4); \
    _Pragma("unroll") \
    for (int j_ = 0; j_ < 4; ++j_) { \
      _Float16 h0_ = (_Float16)va_[j_]; \
      (HI)[j_]     = h0_; \
      (LO)[j_]     = (_Float16)(va_[j_] - (float)h0_); \
      _Float16 h1_ = (_Float16)vb_[j_]; \
      (HI)[j_ + 4] = h1_; \
      (LO)[j_ + 4] = (_Float16)(vb_[j_] - (float)h1_); \
    } \
  } while (0)

// single-tile matmul stage: O = frag(B) @ A^T + bias ; packed conflict-free LDS
// reads; 3-product hi/lo split (uh*Wh + uh*Wl + ul*Wh), 3 chains of depth 4.
#define STG(BH, BL, AH, AL, BI, O) do { \
    f32x4 c_ = (BI); \
    f32x4 e_ = {0.f,0.f,0.f,0.f}, f_ = {0.f,0.f,0.f,0.f}; \
    _Pragma("unroll") \
    for (int ks_ = 0; ks_ < 4; ++ks_) { \
      const f16x8 uh_ = *(const f16x8*)(&(BH)[(ks_*64 + l)*8]); \
      const f16x8 ul_ = *(const f16x8*)(&(BL)[(ks_*64 + l)*8]); \
      c_ = MFMA16((AH)[ks_], uh_, c_); \
      e_ = MFMA16((AL)[ks_], uh_, e_); \
      f_ = MFMA16((AH)[ks_], ul_, f_); \
    } \
    (O) = c_ + e_ + f_; \
  } while (0)

// write this lane's 4 channels (chans ch0+4g..+3 of batch row r) into the
// packed hi/lo frag arrays at precomputed slot wb0 (one ds_write_b64 each)
#define WPK(DH, DL, V) do { \
    f16x4 wh_, wl_; \
    _Pragma("unroll") \
    for (int q_ = 0; q_ < 4; ++q_) { \
      _Float16 hh_ = (_Float16)(V)[q_]; \
      wh_[q_] = hh_; wl_[q_] = (_Float16)((V)[q_] - (float)hh_); \
    } \
    *(f16x4*)(&(DH)[wb0]) = wh_; \
    *(f16x4*)(&(DL)[wb0]) = wl_; \
  } while (0)

__device__ inline f32x4 tanh4(f32x4 z) {
  f32x4 o;
  #pragma unroll
  for (int q = 0; q < 4; ++q) {
    float zz = fminf(fmaxf(z[q], -15.f), 15.f);
    float e  = __builtin_amdgcn_exp2f(2.8853900817779268f * zz); // e^(2x)
    o[q] = (e - 1.f) * __builtin_amdgcn_rcpf(e + 1.f);
  }
  return o;
}

__global__ __launch_bounds__(512, 2) void node_rk4_kernel(
    const float* __restrict__ x,    const float* __restrict__ Win,
    const float* __restrict__ binp, const float* __restrict__ W1,
    const float* __restrict__ b1,   const float* __restrict__ Wout,
    const float* __restrict__ bout, const float* __restrict__ ws,
    float* __restrict__ out)
{
  // packed frag buffers: slot (ks,lane) holds 8 halves = chans [32ks+8*(l>>4)..+8) of row l&15
  __shared__ _Float16 bufA_hi[2048], bufA_lo[2048], bufB_hi[2048], bufB_lo[2048];

  const int tid = (int)threadIdx.x;
  const int w   = tid >> 6;   // wave 0..7, owns channels [16w, 16w+16)
  const int l   = tid & 63;
  const int g   = l >> 4;
  const int r   = l & 15;     // batch row within tile
  const int rowbase = (int)blockIdx.x * ROWS;
  const int ch0 = w * 16;
  // packed write slot for chans ch0+4g+q of row r
  const int wb0 = ((w >> 1)*512 + (2*(w & 1) + (g >> 1))*128 + r*8) + 4*(g & 1);

  // ---------- persistent weight fragments ----------
  f16x8 Gh[4], Gl[4];              // G rows [ch0+r][*] for this wave's 16 chans
  #pragma unroll
  for (int ks = 0; ks < 4; ++ks)
    SPLIT8(ws + WS_G + (size_t)(ch0 + r)*Hsz + 32*ks + 8*g, Gh[ks], Gl[ks]);

  f16x8 goh[4], gol[4];            // Go rows (8 real, padded to 16) — used by wave 0
  #pragma unroll
  for (int ks = 0; ks < 4; ++ks) {
    if (r < OUTsz) SPLIT8(ws + WS_GO + (size_t)r*Hsz + 32*ks + 8*g, goh[ks], gol[ks]);
    else {
      #pragma unroll
      for (int j = 0; j < 8; ++j) { goh[ks][j] = (_Float16)0.f; gol[ks][j] = (_Float16)0.f; }
    }
  }

  // bias vectors (acc reg q <-> chan ch0+4g+q)
  const f32x4 dv  = *(const f32x4*)(ws + WS_D + ch0 + 4*g);
  const f32x4 dv6 = 6.f * dv;
  f32x4 cov6, boutv;
  if (g < 2) { cov6 = 6.f * *(const f32x4*)(ws + WS_CO + 4*g);
               boutv = *(const f32x4*)(bout + 4*g); }
  else { cov6 = f32x4{0.f,0.f,0.f,0.f}; boutv = f32x4{0.f,0.f,0.f,0.f}; }

  // ---------- y0 = x[:, S-1, :] @ Win^T + bin (this lane's 4 chans) ----------
  const float* xr = x + ((size_t)(rowbase + r)*Ssz + (Ssz - 1))*INsz;
  const f32x4 xa = *(const f32x4*)xr;
  const f32x4 xb = *(const f32x4*)(xr + 4);
  f32x4 yv;
  {
    const f32x4 binv = *(const f32x4*)(binp + ch0 + 4*g);
    #pragma unroll
    for (int q = 0; q < 4; ++q) {
      const float* wrp = Win + (size_t)(ch0 + 4*g + q)*INsz;
      const f32x4 wa = *(const f32x4*)wrp;
      const f32x4 wb = *(const f32x4*)(wrp + 4);
      float acc = binv[q];
      #pragma unroll
      for (int i = 0; i < 4; ++i) acc += xa[i]*wa[i] + xb[i]*wb[i];
      yv[q] = acc;
    }
  }

  WPK(bufA_hi, bufA_lo, yv);   // stage y0 frags
  __syncthreads();

  // ---------- init: z = y0@W1^T + b1 (all waves), o = y0@Wout^T (wave 0) ----------
  f32x4 z, o;
  {
    f16x8 a1h[4], a1l[4];           // transient W1 frags
    #pragma unroll
    for (int ks = 0; ks < 4; ++ks)
      SPLIT8(W1 + (size_t)(ch0 + r)*Hsz + 32*ks + 8*g, a1h[ks], a1l[ks]);
    const f32x4 b1v = *(const f32x4*)(b1 + ch0 + 4*g);
    STG(bufA_hi, bufA_lo, a1h, a1l, b1v, z);

    if (w == 0) {
      f16x8 woh[4], wol[4];         // transient Wout frags (padded)
      #pragma unroll
      for (int ks = 0; ks < 4; ++ks) {
        if (r < OUTsz) SPLIT8(Wout + (size_t)r*Hsz + 32*ks + 8*g, woh[ks], wol[ks]);
        else {
          #pragma unroll
          for (int j = 0; j < 8; ++j) { woh[ks][j] = (_Float16)0.f; wol[ks][j] = (_Float16)0.f; }
        }
      }
      const f32x4 zero = {0.f,0.f,0.f,0.f};
      STG(bufA_hi, bufA_lo, woh, wol, zero, o);
    } else {
      o = f32x4{0.f,0.f,0.f,0.f};
    }
  }
  __syncthreads();   // bufA readers done before loop's s1 overwrites it

  // ---------- RK4 in z-space: 4 matmuls + 4 barriers per step ----------
  f32x4 Ta, m, t;
  #pragma unroll 1
  for (int p = 0; p < Psz; ++p) {
    if (w == 0 && g < 2) {   // out_p = o + bout (lane covers out chans 4g..4g+3 of row r)
      float* dst = out + ((size_t)(rowbase + r)*Psz + p)*OUTsz + 4*g;
      *(f32x4*)dst = o + boutv;
    }
    if (p == Psz - 1) break;

    // s1: t1 = tanh(z) ; Ta = t1 ; -> bufA
    t = tanh4(z);
    Ta = t;
    WPK(bufA_hi, bufA_lo, t);
    __syncthreads();

    // s2: m = t1@G^T + d ; t2 = tanh(z + 0.5m) -> bufB
    STG(bufA_hi, bufA_lo, Gh, Gl, dv, m);
    t = tanh4(z + 0.5f*m);
    Ta += 2.f*t;
    WPK(bufB_hi, bufB_lo, t);
    __syncthreads();

    // s3: m = t2@G^T + d ; t3 = tanh(z + 0.5m) -> bufA
    STG(bufB_hi, bufB_lo, Gh, Gl, dv, m);
    t = tanh4(z + 0.5f*m);
    Ta += 2.f*t;
    WPK(bufA_hi, bufA_lo, t);
    __syncthreads();

    // s4: m = t3@G^T + d ; t4 = tanh(z + m) ; T -> bufB
    STG(bufA_hi, bufA_lo, Gh, Gl, dv, m);
    t = tanh4(z + m);
    Ta += t;
    WPK(bufB_hi, bufB_lo, Ta);
    __syncthreads();

    // s5: z += (T@G^T + 6d)/6 ; wave0: o += (T@Go^T + 6co)/6
    STG(bufB_hi, bufB_lo, Gh, Gl, dv6, m);
    z += (1.f/6.f)*m;
    if (w == 0) {
      f32x4 mo;
      STG(bufB_hi, bufB_lo, goh, gol, cov6, mo);
      o += (1.f/6.f)*mo;
    }
    // no barrier needed: s1 writes bufA (last read before s4's barrier); s2's
    // bufB write is after s1's barrier, by which all s5 bufB reads have drained.
  }
}

extern "C" void kernel_launch(void* const* d_in, const int* in_sizes, int n_in,
                              void* d_out, int out_size, void* d_ws, size_t ws_size,
                              hipStream_t stream) {
  (void)in_sizes; (void)n_in; (void)ws_size; (void)out_size;
  const float* x    = (const float*)d_in[0];
  const float* Win  = (const float*)d_in[1];
  const float* binp = (const float*)d_in[2];
  const float* W1   = (const float*)d_in[3];
  const float* b1   = (const float*)d_in[4];
  const float* W2   = (const float*)d_in[5];
  const float* b2   = (const float*)d_in[6];
  const float* Wout = (const float*)d_in[7];
  const float* bout = (const float*)d_in[8];
  float* ws = (float*)d_ws;

  precomp_kernel<<<69, 256, 0, stream>>>(W1, W2, b2, Wout, ws);
  node_rk4_kernel<<<Bsz / ROWS, 512, 0, stream>>>(x, Win, binp, W1, b1, Wout,
                                                  bout, ws, (float*)d_out);
}